// Round 9
// baseline (178.116 us; speedup 1.0000x reference)
//
#include <hip/hip_runtime.h>
#include <hip/hip_bf16.h>
#include <math.h>

#define NB 4096        // batch
#define ED 1024        // embed dim
#define NT 16          // K tiles: ED / 64
#define CHUNKS 128     // 8192 cols / 64 per-wave chunk
#define GEMM_GRID 512  // (4096/256) * (8192/256)

typedef __attribute__((ext_vector_type(8))) short bf16x8;
typedef __attribute__((ext_vector_type(4))) float f32x4;

#define AS1 __attribute__((address_space(1)))
#define AS3 __attribute__((address_space(3)))

__device__ inline unsigned short f2bf(float x) {
    unsigned u = __builtin_bit_cast(unsigned, x);
    unsigned r = (u + 0x7fffu + ((u >> 16) & 1u)) >> 16;
    return (unsigned short)r;
}

// ---------- Kernel 1: L2-normalize rows -> bf16. One wave per row. ----------
__global__ __launch_bounds__(256) void normalize_cast(
    const float* __restrict__ q, const float* __restrict__ p,
    const float* __restrict__ n,
    unsigned short* __restrict__ Abf, unsigned short* __restrict__ Bbf)
{
    const int w = threadIdx.x >> 6, l = threadIdx.x & 63;
    const int row = blockIdx.x * 4 + w;          // 0..12287
    const int mat = row >> 12;
    const int r = row & 4095;
    const float* src = (mat == 0) ? q : (mat == 1 ? p : n);
    src += (size_t)r * ED;
    unsigned short* dst = (mat == 0) ? (Abf + (size_t)r * ED)
                                     : (Bbf + ((size_t)(mat - 1) * NB + r) * ED);
    float4 v[4];
    #pragma unroll
    for (int i = 0; i < 4; ++i)
        v[i] = *(const float4*)(src + (size_t)(i * 64 + l) * 4);
    float ss = 0.f;
    #pragma unroll
    for (int i = 0; i < 4; ++i)
        ss += v[i].x * v[i].x + v[i].y * v[i].y + v[i].z * v[i].z + v[i].w * v[i].w;
    #pragma unroll
    for (int off = 1; off < 64; off <<= 1) ss += __shfl_xor(ss, off, 64);
    const float inv = 1.0f / fmaxf(sqrtf(ss), 1e-12f);
    #pragma unroll
    for (int i = 0; i < 4; ++i) {
        ushort4 o;
        o.x = f2bf(v[i].x * inv); o.y = f2bf(v[i].y * inv);
        o.z = f2bf(v[i].z * inv); o.w = f2bf(v[i].w * inv);
        *(ushort4*)(dst + (size_t)(i * 64 + l) * 4) = o;
    }
}

// ---------- Kernel 2: R5 structure (256x256, BK=64, 8 waves 2Mx4N, 2 barriers
// per K-tile, vmcnt(8) staging, T2 swizzle, 2D-XCD rect) + R9 change:
// SUB-STEP SOFTWARE PIPELINE — issue both substeps' 24 ds_reads into separate
// reg sets, counted lgkmcnt(12) -> MFMA s0 overlaps s1's LDS drain. ----------
__global__ __launch_bounds__(512, 2) void gemm_fused(
    const unsigned short* __restrict__ Abf, const unsigned short* __restrict__ Bbf,
    float* __restrict__ part_m, float* __restrict__ part_s,
    float* __restrict__ diag)
{
    extern __shared__ char smem[];   // A: [2][256 rows][128B] at 0; B at 65536

    // ---- 2D XCD-rectangle swizzle (proven R5: FETCH 135->49 MB) ----
    const int bid = blockIdx.x;
    const int xcd = bid & 7;
    const int idx = bid >> 3;             // 0..63 within rectangle
    const int lr  = idx >> 3;             // 0..7
    const int lcr = idx & 7;
    const int lc  = (lr & 1) ? (7 - lcr) : lcr;
    const int rt  = (xcd & 1) * 8 + lr;   // 0..15
    const int ct  = (xcd >> 1) * 8 + lc;  // 0..31

    const int tid = threadIdx.x;
    const int w = tid >> 6, l = tid & 63;
    const int wm = w >> 2, wn = w & 3;

    // ---- staging addresses (pre-swizzled global source, linear LDS dest) ----
    const int srow = tid >> 3;                           // 0..63
    const int scol = ((tid & 7) ^ (srow & 7)) << 3;      // inverse-swizzled col
    const unsigned short* gA = Abf + (size_t)(rt * 256 + srow) * ED + scol;
    const unsigned short* gB = Bbf + (size_t)(ct * 256 + srow) * ED + scol;
    char* const ldsAw = smem + w * 1024;                 // + buf*32768 + j*8192
    char* const ldsBw = smem + 65536 + w * 1024;

#define STAGE(kt, b) do {                                                        \
    const unsigned short* _ga = gA + (kt) * 64;                                  \
    const unsigned short* _gb = gB + (kt) * 64;                                  \
    _Pragma("unroll")                                                            \
    for (int j = 0; j < 4; ++j)                                                  \
        __builtin_amdgcn_global_load_lds(                                        \
            (const AS1 void*)(_ga + (size_t)j * 64 * ED),                        \
            (AS3 void*)(ldsAw + (b) * 32768 + j * 8192), 16, 0, 0);              \
    _Pragma("unroll")                                                            \
    for (int j = 0; j < 4; ++j)                                                  \
        __builtin_amdgcn_global_load_lds(                                        \
            (const AS1 void*)(_gb + (size_t)j * 64 * ED),                        \
            (AS3 void*)(ldsBw + (b) * 32768 + j * 8192), 16, 0, 0);              \
} while (0)

    f32x4 acc[8][4];
    #pragma unroll
    for (int m = 0; m < 8; ++m)
        #pragma unroll
        for (int nn = 0; nn < 4; ++nn)
            acc[m][nn] = (f32x4)0.0f;

    const int frow = l & 15;
    const int fsel = (l >> 4) << 4;          // 0,16,32,48 (byte)
    const int xm   = (l & 7) << 4;           // XOR swizzle mask (byte)

#define LDA(Ab, m, s) (*(const bf16x8*)((Ab) + (wm * 128 + (m) * 16 + frow) * 128 + (((s) * 64 + fsel) ^ xm)))
#define LDB(Bb, nn, s) (*(const bf16x8*)((Bb) + (wn * 64 + (nn) * 16 + frow) * 128 + (((s) * 64 + fsel) ^ xm)))

    // ---- prologue: stage tiles 0,1; wait tile 0 ----
    STAGE(0, 0);
    STAGE(1, 1);
    asm volatile("s_waitcnt vmcnt(8)" ::: "memory");
    __builtin_amdgcn_s_barrier();
    __builtin_amdgcn_sched_barrier(0);

    for (int t = 0; t < NT; ++t) {
        const int b = t & 1;
        const char* Ab = smem + b * 32768;
        const char* Bb = smem + 65536 + b * 32768;

        // issue ALL 24 ds_reads up front, into independent register sets
        bf16x8 a0[8], b0[4], a1[8], b1[4];
        #pragma unroll
        for (int m = 0; m < 8; ++m) a0[m] = LDA(Ab, m, 0);
        #pragma unroll
        for (int nn = 0; nn < 4; ++nn) b0[nn] = LDB(Bb, nn, 0);
        #pragma unroll
        for (int m = 0; m < 8; ++m) a1[m] = LDA(Ab, m, 1);
        #pragma unroll
        for (int nn = 0; nn < 4; ++nn) b1[nn] = LDB(Bb, nn, 1);

        // counted wait: only s0's 12 reads must be done; s1's 12 stay in flight
        asm volatile("s_waitcnt lgkmcnt(12)" ::: "memory");
        __builtin_amdgcn_sched_barrier(0);
        __builtin_amdgcn_s_setprio(1);
        #pragma unroll
        for (int m = 0; m < 8; ++m)
            #pragma unroll
            for (int nn = 0; nn < 4; ++nn)
                acc[m][nn] = __builtin_amdgcn_mfma_f32_16x16x32_bf16(
                    a0[m], b0[nn], acc[m][nn], 0, 0, 0);
        __builtin_amdgcn_s_setprio(0);

        asm volatile("s_waitcnt lgkmcnt(0)" ::: "memory");
        __builtin_amdgcn_sched_barrier(0);
        __builtin_amdgcn_s_setprio(1);
        #pragma unroll
        for (int m = 0; m < 8; ++m)
            #pragma unroll
            for (int nn = 0; nn < 4; ++nn)
                acc[m][nn] = __builtin_amdgcn_mfma_f32_16x16x32_bf16(
                    a1[m], b1[nn], acc[m][nn], 0, 0, 0);
        __builtin_amdgcn_s_setprio(0);

        if (t == NT - 1) break;
        // all waves' reads of buf b retired (own lgkmcnt(0) above) -> barrier,
        // then safe to overwrite buf b with tile t+2.
        __builtin_amdgcn_s_barrier();
        __builtin_amdgcn_sched_barrier(0);
        if (t + 2 < NT) {
            STAGE(t + 2, b);
            asm volatile("s_waitcnt vmcnt(8)" ::: "memory");   // tile t+1 landed
        } else {
            asm volatile("s_waitcnt vmcnt(0)" ::: "memory");   // tail drain
        }
        __builtin_amdgcn_sched_barrier(0);
        __builtin_amdgcn_s_barrier();
        __builtin_amdgcn_sched_barrier(0);
    }
#undef STAGE
#undef LDA
#undef LDB

    // ---- epilogue: x20 scale, per-wave 64-col chunk (max, sum-exp), diag ----
    const float SCALE = 20.0f;   // 1 / 0.05
    const int chunk = ct * 4 + wn;
    const int rbase = rt * 256 + wm * 128;
    const int g = l >> 4;
    #pragma unroll
    for (int m = 0; m < 8; ++m) {
        #pragma unroll
        for (int j = 0; j < 4; ++j) {
            float v0 = acc[m][0][j] * SCALE;
            float v1 = acc[m][1][j] * SCALE;
            float v2 = acc[m][2][j] * SCALE;
            float v3 = acc[m][3][j] * SCALE;
            const int row_in_block = wm * 128 + m * 16 + g * 4 + j;
            if (ct == rt) {   // diagonal (labels[i]=i, pos half cols)
                #pragma unroll
                for (int nn = 0; nn < 4; ++nn) {
                    const int col_in_block = wn * 64 + nn * 16 + (l & 15);
                    float vv = (nn == 0) ? v0 : (nn == 1) ? v1 : (nn == 2) ? v2 : v3;
                    if (col_in_block == row_in_block)
                        diag[rt * 256 + row_in_block] = vv;
                }
            }
            float mx = fmaxf(fmaxf(v0, v1), fmaxf(v2, v3));
            #pragma unroll
            for (int off = 1; off < 16; off <<= 1)
                mx = fmaxf(mx, __shfl_xor(mx, off, 64));
            float sum = __expf(v0 - mx) + __expf(v1 - mx)
                      + __expf(v2 - mx) + __expf(v3 - mx);
            #pragma unroll
            for (int off = 1; off < 16; off <<= 1)
                sum += __shfl_xor(sum, off, 64);
            if ((l & 15) == 0) {
                const int R = rbase + m * 16 + g * 4 + j;
                part_m[(size_t)chunk * NB + R] = mx;
                part_s[(size_t)chunk * NB + R] = sum;
            }
        }
    }
}

// ---------- Kernel 3: merge 128 per-chunk partials per row, reduce loss ----------
__global__ __launch_bounds__(256) void combine(
    const float* __restrict__ part_m, const float* __restrict__ part_s,
    const float* __restrict__ diag, float* __restrict__ out)
{
    const int l = threadIdx.x & 63;
    const int strip = threadIdx.x >> 6;
    const int R = blockIdx.x * 64 + l;

    float M = -INFINITY;
    #pragma unroll 8
    for (int i = strip * 32; i < strip * 32 + 32; ++i)
        M = fmaxf(M, part_m[(size_t)i * NB + R]);
    float S = 0.0f;
    #pragma unroll 8
    for (int i = strip * 32; i < strip * 32 + 32; ++i)
        S += part_s[(size_t)i * NB + R] * __expf(part_m[(size_t)i * NB + R] - M);

    __shared__ float sm[4][64], ssum[4][64];
    sm[strip][l] = M; ssum[strip][l] = S;
    __syncthreads();
    if (strip == 0) {
        float Mf = fmaxf(fmaxf(sm[0][l], sm[1][l]), fmaxf(sm[2][l], sm[3][l]));
        float Sf = 0.0f;
        #pragma unroll
        for (int k = 0; k < 4; ++k)
            Sf += ssum[k][l] * __expf(sm[k][l] - Mf);
        float li = (Mf + logf(Sf)) - diag[R];
        #pragma unroll
        for (int off = 1; off < 64; off <<= 1) li += __shfl_xor(li, off, 64);
        if (l == 0) atomicAdd(out, li * (1.0f / (float)NB));
    }
}

extern "C" void kernel_launch(void* const* d_in, const int* in_sizes, int n_in,
                              void* d_out, int out_size, void* d_ws, size_t ws_size,
                              hipStream_t stream) {
    const float* q = (const float*)d_in[0];
    const float* p = (const float*)d_in[1];
    const float* n = (const float*)d_in[2];
    char* wsb = (char*)d_ws;
    // ws: Abf 8MB | Bbf 16MB | part_m 2MB | part_s 2MB | diag 16KB
    unsigned short* Abf = (unsigned short*)(wsb);
    unsigned short* Bbf = (unsigned short*)(wsb + ((size_t)8 << 20));
    float* part_m = (float*)(wsb + ((size_t)24 << 20));
    float* part_s = (float*)(wsb + ((size_t)26 << 20));
    float* diag   = (float*)(wsb + ((size_t)28 << 20));
    float* out = (float*)d_out;

    (void)hipFuncSetAttribute(reinterpret_cast<const void*>(&gemm_fused),
                              hipFuncAttributeMaxDynamicSharedMemorySize, 131072);

    hipMemsetAsync(out, 0, sizeof(float), stream);
    normalize_cast<<<3 * NB / 4, 256, 0, stream>>>(q, p, n, Abf, Bbf);
    gemm_fused<<<GEMM_GRID, 512, 131072, stream>>>(Abf, Bbf, part_m, part_s, diag);
    combine<<<NB / 64, 256, 0, stream>>>(part_m, part_s, diag, out);
}

// Round 10
// 175.392 us; speedup vs baseline: 1.0155x; 1.0155x over previous
//
#include <hip/hip_runtime.h>
#include <hip/hip_bf16.h>
#include <math.h>

#define NB 4096        // batch
#define ED 1024        // embed dim
#define NT 16          // K tiles: ED / 64
#define CHUNKS 128     // 8192 cols / 64 per-wave chunk
#define GEMM_GRID 512  // (4096/256) * (8192/256)

typedef __attribute__((ext_vector_type(8))) short bf16x8;
typedef __attribute__((ext_vector_type(4))) float f32x4;

#define AS1 __attribute__((address_space(1)))
#define AS3 __attribute__((address_space(3)))

__device__ inline unsigned short f2bf(float x) {
    unsigned u = __builtin_bit_cast(unsigned, x);
    unsigned r = (u + 0x7fffu + ((u >> 16) & 1u)) >> 16;
    return (unsigned short)r;
}

// ---------- Kernel 1: L2-normalize rows -> bf16. One wave per row.
// R10: also zeroes the scalar output (replaces the hipMemsetAsync node). ----------
__global__ __launch_bounds__(256) void normalize_cast(
    const float* __restrict__ q, const float* __restrict__ p,
    const float* __restrict__ n,
    unsigned short* __restrict__ Abf, unsigned short* __restrict__ Bbf,
    float* __restrict__ outz)
{
    if (blockIdx.x == 0 && threadIdx.x == 0) *outz = 0.0f;
    const int w = threadIdx.x >> 6, l = threadIdx.x & 63;
    const int row = blockIdx.x * 4 + w;          // 0..12287
    const int mat = row >> 12;
    const int r = row & 4095;
    const float* src = (mat == 0) ? q : (mat == 1 ? p : n);
    src += (size_t)r * ED;
    unsigned short* dst = (mat == 0) ? (Abf + (size_t)r * ED)
                                     : (Bbf + ((size_t)(mat - 1) * NB + r) * ED);
    float4 v[4];
    #pragma unroll
    for (int i = 0; i < 4; ++i)
        v[i] = *(const float4*)(src + (size_t)(i * 64 + l) * 4);
    float ss = 0.f;
    #pragma unroll
    for (int i = 0; i < 4; ++i)
        ss += v[i].x * v[i].x + v[i].y * v[i].y + v[i].z * v[i].z + v[i].w * v[i].w;
    #pragma unroll
    for (int off = 1; off < 64; off <<= 1) ss += __shfl_xor(ss, off, 64);
    const float inv = 1.0f / fmaxf(sqrtf(ss), 1e-12f);
    #pragma unroll
    for (int i = 0; i < 4; ++i) {
        ushort4 o;
        o.x = f2bf(v[i].x * inv); o.y = f2bf(v[i].y * inv);
        o.z = f2bf(v[i].z * inv); o.w = f2bf(v[i].w * inv);
        *(ushort4*)(dst + (size_t)(i * 64 + l) * 4) = o;
    }
}

// ---------- Kernel 2: R9 structure (256x256, BK=64, 8 waves 2Mx4N, 2 barriers
// per K-tile, vmcnt(8) staging, T2 swizzle, 2D-XCD rect, substep reg pipeline)
// + R10 change: WAVE-PARITY SUBSTEP STAGGER — odd waves issue/compute substep
// 1 before substep 0, so at any instant half the waves drive the LDS pipe and
// half drive the MFMA pipe (break barrier-lockstep pipe alternation). ----------
__global__ __launch_bounds__(512, 2) void gemm_fused(
    const unsigned short* __restrict__ Abf, const unsigned short* __restrict__ Bbf,
    float* __restrict__ part_m, float* __restrict__ part_s,
    float* __restrict__ diag)
{
    extern __shared__ char smem[];   // A: [2][256 rows][128B] at 0; B at 65536

    // ---- 2D XCD-rectangle swizzle (proven R5: FETCH 135->49 MB) ----
    const int bid = blockIdx.x;
    const int xcd = bid & 7;
    const int idx = bid >> 3;             // 0..63 within rectangle
    const int lr  = idx >> 3;             // 0..7
    const int lcr = idx & 7;
    const int lc  = (lr & 1) ? (7 - lcr) : lcr;
    const int rt  = (xcd & 1) * 8 + lr;   // 0..15
    const int ct  = (xcd >> 1) * 8 + lc;  // 0..31

    const int tid = threadIdx.x;
    const int w = tid >> 6, l = tid & 63;
    const int wm = w >> 2, wn = w & 3;

    // ---- staging addresses (pre-swizzled global source, linear LDS dest) ----
    const int srow = tid >> 3;                           // 0..63
    const int scol = ((tid & 7) ^ (srow & 7)) << 3;      // inverse-swizzled col
    const unsigned short* gA = Abf + (size_t)(rt * 256 + srow) * ED + scol;
    const unsigned short* gB = Bbf + (size_t)(ct * 256 + srow) * ED + scol;
    char* const ldsAw = smem + w * 1024;                 // + buf*32768 + j*8192
    char* const ldsBw = smem + 65536 + w * 1024;

#define STAGE(kt, b) do {                                                        \
    const unsigned short* _ga = gA + (kt) * 64;                                  \
    const unsigned short* _gb = gB + (kt) * 64;                                  \
    _Pragma("unroll")                                                            \
    for (int j = 0; j < 4; ++j)                                                  \
        __builtin_amdgcn_global_load_lds(                                        \
            (const AS1 void*)(_ga + (size_t)j * 64 * ED),                        \
            (AS3 void*)(ldsAw + (b) * 32768 + j * 8192), 16, 0, 0);              \
    _Pragma("unroll")                                                            \
    for (int j = 0; j < 4; ++j)                                                  \
        __builtin_amdgcn_global_load_lds(                                        \
            (const AS1 void*)(_gb + (size_t)j * 64 * ED),                        \
            (AS3 void*)(ldsBw + (b) * 32768 + j * 8192), 16, 0, 0);              \
} while (0)

    f32x4 acc[8][4];
    #pragma unroll
    for (int m = 0; m < 8; ++m)
        #pragma unroll
        for (int nn = 0; nn < 4; ++nn)
            acc[m][nn] = (f32x4)0.0f;

    const int frow = l & 15;
    const int fsel = (l >> 4) << 4;          // 0,16,32,48 (byte)
    const int xm   = (l & 7) << 4;           // XOR swizzle mask (byte)
    const int sF   = w & 1;                  // this wave's FIRST substep
    const int sS   = sF ^ 1;                 // second substep

#define LDA(Ab, m, s) (*(const bf16x8*)((Ab) + (wm * 128 + (m) * 16 + frow) * 128 + (((s) * 64 + fsel) ^ xm)))
#define LDB(Bb, nn, s) (*(const bf16x8*)((Bb) + (wn * 64 + (nn) * 16 + frow) * 128 + (((s) * 64 + fsel) ^ xm)))

    // ---- prologue: stage tiles 0,1; wait tile 0 ----
    STAGE(0, 0);
    STAGE(1, 1);
    asm volatile("s_waitcnt vmcnt(8)" ::: "memory");
    __builtin_amdgcn_s_barrier();
    __builtin_amdgcn_sched_barrier(0);

    for (int t = 0; t < NT; ++t) {
        const int b = t & 1;
        const char* Ab = smem + b * 32768;
        const char* Bb = smem + 65536 + b * 32768;

        // issue ALL 24 ds_reads: this wave's FIRST substep (sF) then SECOND (sS)
        bf16x8 aF[8], bF[4], aS[8], bS[4];
        #pragma unroll
        for (int m = 0; m < 8; ++m) aF[m] = LDA(Ab, m, sF);
        #pragma unroll
        for (int nn = 0; nn < 4; ++nn) bF[nn] = LDB(Bb, nn, sF);
        #pragma unroll
        for (int m = 0; m < 8; ++m) aS[m] = LDA(Ab, m, sS);
        #pragma unroll
        for (int nn = 0; nn < 4; ++nn) bS[nn] = LDB(Bb, nn, sS);

        // counted wait: only first-substep's 12 reads must be done
        asm volatile("s_waitcnt lgkmcnt(12)" ::: "memory");
        __builtin_amdgcn_sched_barrier(0);
        __builtin_amdgcn_s_setprio(1);
        #pragma unroll
        for (int m = 0; m < 8; ++m)
            #pragma unroll
            for (int nn = 0; nn < 4; ++nn)
                acc[m][nn] = __builtin_amdgcn_mfma_f32_16x16x32_bf16(
                    aF[m], bF[nn], acc[m][nn], 0, 0, 0);
        __builtin_amdgcn_s_setprio(0);

        asm volatile("s_waitcnt lgkmcnt(0)" ::: "memory");
        __builtin_amdgcn_sched_barrier(0);
        __builtin_amdgcn_s_setprio(1);
        #pragma unroll
        for (int m = 0; m < 8; ++m)
            #pragma unroll
            for (int nn = 0; nn < 4; ++nn)
                acc[m][nn] = __builtin_amdgcn_mfma_f32_16x16x32_bf16(
                    aS[m], bS[nn], acc[m][nn], 0, 0, 0);
        __builtin_amdgcn_s_setprio(0);

        if (t == NT - 1) break;
        // all waves' reads of buf b retired (own lgkmcnt(0) above) -> barrier,
        // then safe to overwrite buf b with tile t+2.
        __builtin_amdgcn_s_barrier();
        __builtin_amdgcn_sched_barrier(0);
        if (t + 2 < NT) {
            STAGE(t + 2, b);
            asm volatile("s_waitcnt vmcnt(8)" ::: "memory");   // tile t+1 landed
        } else {
            asm volatile("s_waitcnt vmcnt(0)" ::: "memory");   // tail drain
        }
        __builtin_amdgcn_sched_barrier(0);
        __builtin_amdgcn_s_barrier();
        __builtin_amdgcn_sched_barrier(0);
    }
#undef STAGE
#undef LDA
#undef LDB

    // ---- epilogue: x20 scale, per-wave 64-col chunk (max, sum-exp), diag ----
    const float SCALE = 20.0f;   // 1 / 0.05
    const int chunk = ct * 4 + wn;
    const int rbase = rt * 256 + wm * 128;
    const int g = l >> 4;
    #pragma unroll
    for (int m = 0; m < 8; ++m) {
        #pragma unroll
        for (int j = 0; j < 4; ++j) {
            float v0 = acc[m][0][j] * SCALE;
            float v1 = acc[m][1][j] * SCALE;
            float v2 = acc[m][2][j] * SCALE;
            float v3 = acc[m][3][j] * SCALE;
            const int row_in_block = wm * 128 + m * 16 + g * 4 + j;
            if (ct == rt) {   // diagonal (labels[i]=i, pos half cols)
                #pragma unroll
                for (int nn = 0; nn < 4; ++nn) {
                    const int col_in_block = wn * 64 + nn * 16 + (l & 15);
                    float vv = (nn == 0) ? v0 : (nn == 1) ? v1 : (nn == 2) ? v2 : v3;
                    if (col_in_block == row_in_block)
                        diag[rt * 256 + row_in_block] = vv;
                }
            }
            float mx = fmaxf(fmaxf(v0, v1), fmaxf(v2, v3));
            #pragma unroll
            for (int off = 1; off < 16; off <<= 1)
                mx = fmaxf(mx, __shfl_xor(mx, off, 64));
            float sum = __expf(v0 - mx) + __expf(v1 - mx)
                      + __expf(v2 - mx) + __expf(v3 - mx);
            #pragma unroll
            for (int off = 1; off < 16; off <<= 1)
                sum += __shfl_xor(sum, off, 64);
            if ((l & 15) == 0) {
                const int R = rbase + m * 16 + g * 4 + j;
                part_m[(size_t)chunk * NB + R] = mx;
                part_s[(size_t)chunk * NB + R] = sum;
            }
        }
    }
}

// ---------- Kernel 3: merge 128 per-chunk partials per row, reduce loss ----------
__global__ __launch_bounds__(256) void combine(
    const float* __restrict__ part_m, const float* __restrict__ part_s,
    const float* __restrict__ diag, float* __restrict__ out)
{
    const int l = threadIdx.x & 63;
    const int strip = threadIdx.x >> 6;
    const int R = blockIdx.x * 64 + l;

    float M = -INFINITY;
    #pragma unroll 8
    for (int i = strip * 32; i < strip * 32 + 32; ++i)
        M = fmaxf(M, part_m[(size_t)i * NB + R]);
    float S = 0.0f;
    #pragma unroll 8
    for (int i = strip * 32; i < strip * 32 + 32; ++i)
        S += part_s[(size_t)i * NB + R] * __expf(part_m[(size_t)i * NB + R] - M);

    __shared__ float sm[4][64], ssum[4][64];
    sm[strip][l] = M; ssum[strip][l] = S;
    __syncthreads();
    if (strip == 0) {
        float Mf = fmaxf(fmaxf(sm[0][l], sm[1][l]), fmaxf(sm[2][l], sm[3][l]));
        float Sf = 0.0f;
        #pragma unroll
        for (int k = 0; k < 4; ++k)
            Sf += ssum[k][l] * __expf(sm[k][l] - Mf);
        float li = (Mf + logf(Sf)) - diag[R];
        #pragma unroll
        for (int off = 1; off < 64; off <<= 1) li += __shfl_xor(li, off, 64);
        if (l == 0) atomicAdd(out, li * (1.0f / (float)NB));
    }
}

extern "C" void kernel_launch(void* const* d_in, const int* in_sizes, int n_in,
                              void* d_out, int out_size, void* d_ws, size_t ws_size,
                              hipStream_t stream) {
    const float* q = (const float*)d_in[0];
    const float* p = (const float*)d_in[1];
    const float* n = (const float*)d_in[2];
    char* wsb = (char*)d_ws;
    // ws: Abf 8MB | Bbf 16MB | part_m 2MB | part_s 2MB | diag 16KB
    unsigned short* Abf = (unsigned short*)(wsb);
    unsigned short* Bbf = (unsigned short*)(wsb + ((size_t)8 << 20));
    float* part_m = (float*)(wsb + ((size_t)24 << 20));
    float* part_s = (float*)(wsb + ((size_t)26 << 20));
    float* diag   = (float*)(wsb + ((size_t)28 << 20));
    float* out = (float*)d_out;

    (void)hipFuncSetAttribute(reinterpret_cast<const void*>(&gemm_fused),
                              hipFuncAttributeMaxDynamicSharedMemorySize, 131072);

    // 3 graph nodes (memset folded into normalize_cast: block 0 zeroes out)
    normalize_cast<<<3 * NB / 4, 256, 0, stream>>>(q, p, n, Abf, Bbf, out);
    gemm_fused<<<GEMM_GRID, 512, 131072, stream>>>(Abf, Bbf, part_m, part_s, diag);
    combine<<<NB / 64, 256, 0, stream>>>(part_m, part_s, diag, out);
}